// Round 1
// baseline (862.330 us; speedup 1.0000x reference)
//
#include <hip/hip_runtime.h>
#include <hip/hip_bf16.h>

namespace {

constexpr int B = 32, S = 512, E = 512, H = 8, P = 64, FF = 1536;
constexpr int BS = B * S;

__device__ __forceinline__ float bf2f(unsigned short u) {
  return __uint_as_float(((unsigned int)u) << 16);
}
__device__ __forceinline__ unsigned short f2bf(float f) {
  __hip_bfloat16 h = __float2bfloat16(f);
  return *reinterpret_cast<unsigned short*>(&h);
}

// K1: xsum[b,e] = sum_s x[b,s,e]   (grid: (B, 8) x 256thr; each block sums 64 rows)
__global__ __launch_bounds__(256) void k_xsum(const float* __restrict__ x, float* __restrict__ xsum) {
  int b = blockIdx.x, ch = blockIdx.y, t = threadIdx.x;
  const float* xp = x + ((size_t)b * S + ch * 64) * E;
  float a0 = 0.f, a1 = 0.f;
  for (int s = 0; s < 64; ++s) {
    a0 += xp[(size_t)s * E + t];
    a1 += xp[(size_t)s * E + t + 256];
  }
  atomicAdd(&xsum[b * E + t], a0);
  atomicAdd(&xsum[b * E + t + 256], a1);
}

// K2: ksum[p]=sum_e xsum[b,e]*wk[h,e,p];  wqk[b,h,e]=0.125*sum_p wq[h,e,p]*ksum[p]
__global__ __launch_bounds__(64) void k_wqk(const float* __restrict__ xsum, const float* __restrict__ wq,
                                            const float* __restrict__ wk, float* __restrict__ wqk) {
  int b = blockIdx.x, h = blockIdx.y;
  int p = threadIdx.x;
  __shared__ float ks[P];
  const float* wkh = wk + (size_t)h * E * P;
  const float* xs = xsum + b * E;
  float acc = 0.f;
  for (int e = 0; e < E; ++e) acc += xs[e] * wkh[e * P + p];
  ks[p] = acc;
  __syncthreads();
  const float* wqh = wq + (size_t)h * E * P;
  for (int k = 0; k < E / 64; ++k) {
    int e = threadIdx.x + k * 64;
    float a = 0.f;
#pragma unroll 8
    for (int pp = 0; pp < P; ++pp) a += wqh[e * P + pp] * ks[pp];
    wqk[((size_t)b * H + h) * E + e] = a * 0.125f;
  }
}

// K3: scores[b,h,s] = x[b,s,:] . wqk[b,h,:]   (grid: (B, S/64) x 256thr)
__global__ __launch_bounds__(256) void k_scores(const float* __restrict__ x, const float* __restrict__ wqk,
                                                float* __restrict__ scores) {
  int b = blockIdx.x, s0 = blockIdx.y * 64, t = threadIdx.x;
  __shared__ float xs[64][68];
  __shared__ float wt[8][68];
  float acc[2] = {0.f, 0.f};
  for (int ec = 0; ec < E; ec += 64) {
#pragma unroll
    for (int j = 0; j < 4; ++j) {
      int i = t + j * 256;
      int row = i >> 4, c4 = i & 15;
      float4 v = *(const float4*)(x + ((size_t)b * S + s0 + row) * E + ec + c4 * 4);
      *(float4*)&xs[row][c4 * 4] = v;
    }
    if (t < 128) {
      int hr = t >> 4, c4 = t & 15;
      float4 v = *(const float4*)(wqk + ((size_t)b * H + hr) * E + ec + c4 * 4);
      *(float4*)&wt[hr][c4 * 4] = v;
    }
    __syncthreads();
#pragma unroll
    for (int j = 0; j < 2; ++j) {
      int o = t + j * 256;
      int sl = o >> 3, hh = o & 7;
      float a = 0.f;
#pragma unroll
      for (int c4 = 0; c4 < 16; ++c4) {
        float4 xa = *(const float4*)&xs[sl][c4 * 4];
        float4 wa = *(const float4*)&wt[hh][c4 * 4];
        a += xa.x * wa.x + xa.y * wa.y + xa.z * wa.z + xa.w * wa.w;
      }
      acc[j] += a;
    }
    __syncthreads();
  }
#pragma unroll
  for (int j = 0; j < 2; ++j) {
    int o = t + j * 256;
    int sl = o >> 3, hh = o & 7;
    scores[((size_t)b * H + hh) * S + s0 + sl] = acc[j];
  }
}

// K4: softmax over s per (b,h); writes attw[b,h,s] (ws) and att_out[b,s,h] (d_out)
__global__ __launch_bounds__(256) void k_softmax(const float* __restrict__ scores, float* __restrict__ attw,
                                                 float* __restrict__ att_out) {
  int bh = blockIdx.x, t = threadIdx.x;
  int b = bh >> 3, h = bh & 7;
  float v0 = scores[(size_t)bh * S + t];
  float v1 = scores[(size_t)bh * S + t + 256];
  float m = fmaxf(v0, v1);
#pragma unroll
  for (int off = 32; off; off >>= 1) m = fmaxf(m, __shfl_xor(m, off));
  __shared__ float rm[4], rs[4];
  if ((t & 63) == 0) rm[t >> 6] = m;
  __syncthreads();
  m = fmaxf(fmaxf(rm[0], rm[1]), fmaxf(rm[2], rm[3]));
  float e0 = __expf(v0 - m), e1 = __expf(v1 - m);
  float sm = e0 + e1;
#pragma unroll
  for (int off = 32; off; off >>= 1) sm += __shfl_xor(sm, off);
  if ((t & 63) == 0) rs[t >> 6] = sm;
  __syncthreads();
  float inv = 1.f / (rs[0] + rs[1] + rs[2] + rs[3]);
  float a0 = e0 * inv, a1 = e1 * inv;
  attw[(size_t)bh * S + t] = a0;
  attw[(size_t)bh * S + t + 256] = a1;
  att_out[((size_t)b * S + t) * H + h] = a0;
  att_out[((size_t)b * S + t + 256) * H + h] = a1;
}

// K5: headout[b,h,s,p] = (x[b,s,:] @ wv[h]) * attw[b,h,s]; accumulate sqnorm[h]
__global__ __launch_bounds__(256) void k_vproj(const float* __restrict__ x, const float* __restrict__ wv,
                                               const float* __restrict__ attw, float* __restrict__ headout,
                                               float* __restrict__ sqnorm) {
  int bh = blockIdx.x;
  int b = bh >> 3, h = bh & 7;
  int s0 = blockIdx.y * 64;
  int t = threadIdx.x, tx = t & 15, ty = t >> 4;
  __shared__ float As[16][68];
  __shared__ float Bs[16][68];
  float acc[4][4] = {};
  const float* xb = x + ((size_t)b * S + s0) * E;
  const float* wvh = wv + (size_t)h * E * P;
  for (int kc = 0; kc < E; kc += 16) {
    {
      int r = t >> 2, c4 = t & 3;
      float4 a = *(const float4*)(xb + (size_t)r * E + kc + c4 * 4);
      As[c4 * 4 + 0][r] = a.x;
      As[c4 * 4 + 1][r] = a.y;
      As[c4 * 4 + 2][r] = a.z;
      As[c4 * 4 + 3][r] = a.w;
    }
    {
      int c = t >> 4, p4 = t & 15;
      float4 v = *(const float4*)(wvh + (size_t)(kc + c) * P + p4 * 4);
      *(float4*)&Bs[c][p4 * 4] = v;
    }
    __syncthreads();
#pragma unroll
    for (int k = 0; k < 16; ++k) {
      float4 a = *(const float4*)&As[k][ty * 4];
      float4 bv = *(const float4*)&Bs[k][tx * 4];
      float av[4] = {a.x, a.y, a.z, a.w};
      float bw[4] = {bv.x, bv.y, bv.z, bv.w};
#pragma unroll
      for (int i = 0; i < 4; ++i)
#pragma unroll
        for (int j = 0; j < 4; ++j) acc[i][j] += av[i] * bw[j];
    }
    __syncthreads();
  }
  const float* aw = attw + (size_t)bh * S + s0;
  float ssq = 0.f;
#pragma unroll
  for (int i = 0; i < 4; ++i) {
    int s = ty * 4 + i;
    float w = aw[s];
    float4 o;
    o.x = acc[i][0] * w;
    o.y = acc[i][1] * w;
    o.z = acc[i][2] * w;
    o.w = acc[i][3] * w;
    ssq += o.x * o.x + o.y * o.y + o.z * o.z + o.w * o.w;
    *(float4*)(headout + (((size_t)bh * S) + s0 + s) * P + tx * 4) = o;
  }
#pragma unroll
  for (int off = 32; off; off >>= 1) ssq += __shfl_xor(ssq, off);
  __shared__ float rs[4];
  if ((t & 63) == 0) rs[t >> 6] = ssq;
  __syncthreads();
  if (t == 0) atomicAdd(&sqnorm[h], rs[0] + rs[1] + rs[2] + rs[3]);
}

// K6: h = LN0(merged + x), merged[b,s,p*H+h] = headout[b,h,s,p]*rsqrt(sqnorm[h])
__global__ __launch_bounds__(256) void k_ln0(const float* __restrict__ headout, const float* __restrict__ x,
                                             const float* __restrict__ sqnorm, const float* __restrict__ g,
                                             const float* __restrict__ bb, float* __restrict__ hbuf) {
  int r = blockIdx.x;
  int b = r >> 9, s = r & 511;
  int t = threadIdx.x;
  float v[2];
#pragma unroll
  for (int j = 0; j < 2; ++j) {
    int e = t + j * 256;
    int h = e & 7, p = e >> 3;
    float hs = rsqrtf(fmaxf(sqnorm[h], 1e-12f));
    v[j] = headout[(((size_t)b * H + h) * S + s) * P + p] * hs + x[(size_t)r * E + e];
  }
  float sum = v[0] + v[1];
  float sq = v[0] * v[0] + v[1] * v[1];
#pragma unroll
  for (int off = 32; off; off >>= 1) {
    sum += __shfl_xor(sum, off);
    sq += __shfl_xor(sq, off);
  }
  __shared__ float r0[4], r1[4];
  if ((t & 63) == 0) { r0[t >> 6] = sum; r1[t >> 6] = sq; }
  __syncthreads();
  sum = r0[0] + r0[1] + r0[2] + r0[3];
  sq = r1[0] + r1[1] + r1[2] + r1[3];
  float mean = sum * (1.f / E);
  float var = fmaxf(sq * (1.f / E) - mean * mean, 0.f);
  float rstd = rsqrtf(var + 1e-3f);
#pragma unroll
  for (int j = 0; j < 2; ++j) {
    int e = t + j * 256;
    hbuf[(size_t)r * E + e] = (v[j] - mean) * rstd * g[e] + bb[e];
  }
}

// K7: p1 = bf16(leaky_relu(hbuf @ w1 + b1))   M=BS,N=FF,K=E ; 64x64 tile
__global__ __launch_bounds__(256) void k_ffn1(const float* __restrict__ hbuf, const float* __restrict__ w1,
                                              const float* __restrict__ b1, unsigned short* __restrict__ p1) {
  int r0 = blockIdx.x * 64, f0 = blockIdx.y * 64;
  int t = threadIdx.x, tx = t & 15, ty = t >> 4;
  __shared__ float As[16][68];
  __shared__ float Bs[16][68];
  float acc[4][4] = {};
  for (int kc = 0; kc < E; kc += 16) {
    {
      int rr = t >> 2, c4 = t & 3;
      float4 a = *(const float4*)(hbuf + (size_t)(r0 + rr) * E + kc + c4 * 4);
      As[c4 * 4 + 0][rr] = a.x;
      As[c4 * 4 + 1][rr] = a.y;
      As[c4 * 4 + 2][rr] = a.z;
      As[c4 * 4 + 3][rr] = a.w;
    }
    {
      int c = t >> 4, p4 = t & 15;
      float4 v = *(const float4*)(w1 + (size_t)(kc + c) * FF + f0 + p4 * 4);
      *(float4*)&Bs[c][p4 * 4] = v;
    }
    __syncthreads();
#pragma unroll
    for (int k = 0; k < 16; ++k) {
      float4 a = *(const float4*)&As[k][ty * 4];
      float4 bv = *(const float4*)&Bs[k][tx * 4];
      float av[4] = {a.x, a.y, a.z, a.w};
      float bw[4] = {bv.x, bv.y, bv.z, bv.w};
#pragma unroll
      for (int i = 0; i < 4; ++i)
#pragma unroll
        for (int j = 0; j < 4; ++j) acc[i][j] += av[i] * bw[j];
    }
    __syncthreads();
  }
  float4 bv = *(const float4*)(b1 + f0 + tx * 4);
  float bw[4] = {bv.x, bv.y, bv.z, bv.w};
#pragma unroll
  for (int i = 0; i < 4; ++i) {
    int row = r0 + ty * 4 + i;
    float v0 = acc[i][0] + bw[0]; v0 = v0 > 0.f ? v0 : 0.2f * v0;
    float v1 = acc[i][1] + bw[1]; v1 = v1 > 0.f ? v1 : 0.2f * v1;
    float v2 = acc[i][2] + bw[2]; v2 = v2 > 0.f ? v2 : 0.2f * v2;
    float v3 = acc[i][3] + bw[3]; v3 = v3 > 0.f ? v3 : 0.2f * v3;
    ushort4 u;
    u.x = f2bf(v0); u.y = f2bf(v1); u.z = f2bf(v2); u.w = f2bf(v3);
    *(ushort4*)(p1 + (size_t)row * FF + f0 + tx * 4) = u;
  }
}

// K7b: rinv[r] = rsqrt(max(sum_f p1[r,f]^2, 1e-12))
__global__ __launch_bounds__(256) void k_rownorm(const unsigned int* __restrict__ p1u, float* __restrict__ rinv) {
  int r = blockIdx.x, t = threadIdx.x;
  const unsigned int* row = p1u + (size_t)r * (FF / 2);
  float ss = 0.f;
#pragma unroll
  for (int j = 0; j < 3; ++j) {
    unsigned int u = row[t + j * 256];
    float lo = __uint_as_float(u << 16);
    float hi = __uint_as_float(u & 0xffff0000u);
    ss += lo * lo + hi * hi;
  }
#pragma unroll
  for (int off = 32; off; off >>= 1) ss += __shfl_xor(ss, off);
  __shared__ float rs[4];
  if ((t & 63) == 0) rs[t >> 6] = ss;
  __syncthreads();
  if (t == 0) rinv[r] = rsqrtf(fmaxf(rs[0] + rs[1] + rs[2] + rs[3], 1e-12f));
}

// K8: p2r = (p1 @ w2)*rinv[row] + b2 + hbuf   M=BS,N=E,K=FF
__global__ __launch_bounds__(256) void k_ffn2(const unsigned short* __restrict__ p1, const float* __restrict__ w2,
                                              const float* __restrict__ rinv, const float* __restrict__ b2,
                                              const float* __restrict__ hbuf, float* __restrict__ p2r) {
  int r0 = blockIdx.x * 64, e0 = blockIdx.y * 64;
  int t = threadIdx.x, tx = t & 15, ty = t >> 4;
  __shared__ float As[16][68];
  __shared__ float Bs[16][68];
  float acc[4][4] = {};
  for (int kc = 0; kc < FF; kc += 16) {
    {
      int rr = t >> 2, c4 = t & 3;
      ushort4 a = *(const ushort4*)(p1 + (size_t)(r0 + rr) * FF + kc + c4 * 4);
      As[c4 * 4 + 0][rr] = bf2f(a.x);
      As[c4 * 4 + 1][rr] = bf2f(a.y);
      As[c4 * 4 + 2][rr] = bf2f(a.z);
      As[c4 * 4 + 3][rr] = bf2f(a.w);
    }
    {
      int c = t >> 4, p4 = t & 15;
      float4 v = *(const float4*)(w2 + (size_t)(kc + c) * E + e0 + p4 * 4);
      *(float4*)&Bs[c][p4 * 4] = v;
    }
    __syncthreads();
#pragma unroll
    for (int k = 0; k < 16; ++k) {
      float4 a = *(const float4*)&As[k][ty * 4];
      float4 bv = *(const float4*)&Bs[k][tx * 4];
      float av[4] = {a.x, a.y, a.z, a.w};
      float bw[4] = {bv.x, bv.y, bv.z, bv.w};
#pragma unroll
      for (int i = 0; i < 4; ++i)
#pragma unroll
        for (int j = 0; j < 4; ++j) acc[i][j] += av[i] * bw[j];
    }
    __syncthreads();
  }
  float4 b2v = *(const float4*)(b2 + e0 + tx * 4);
  float bw[4] = {b2v.x, b2v.y, b2v.z, b2v.w};
#pragma unroll
  for (int i = 0; i < 4; ++i) {
    int row = r0 + ty * 4 + i;
    float ri = rinv[row];
    float4 hv = *(const float4*)(hbuf + (size_t)row * E + e0 + tx * 4);
    float4 o;
    o.x = acc[i][0] * ri + bw[0] + hv.x;
    o.y = acc[i][1] * ri + bw[1] + hv.y;
    o.z = acc[i][2] * ri + bw[2] + hv.z;
    o.w = acc[i][3] * ri + bw[3] + hv.w;
    *(float4*)(p2r + (size_t)row * E + e0 + tx * 4) = o;
  }
}

// K9: out = LN1(p2r)
__global__ __launch_bounds__(256) void k_ln1(const float* __restrict__ p2r, const float* __restrict__ g,
                                             const float* __restrict__ bb, float* __restrict__ outp) {
  int r = blockIdx.x, t = threadIdx.x;
  float v[2];
#pragma unroll
  for (int j = 0; j < 2; ++j) v[j] = p2r[(size_t)r * E + t + j * 256];
  float sum = v[0] + v[1];
  float sq = v[0] * v[0] + v[1] * v[1];
#pragma unroll
  for (int off = 32; off; off >>= 1) {
    sum += __shfl_xor(sum, off);
    sq += __shfl_xor(sq, off);
  }
  __shared__ float r0[4], r1[4];
  if ((t & 63) == 0) { r0[t >> 6] = sum; r1[t >> 6] = sq; }
  __syncthreads();
  sum = r0[0] + r0[1] + r0[2] + r0[3];
  sq = r1[0] + r1[1] + r1[2] + r1[3];
  float mean = sum * (1.f / E);
  float var = fmaxf(sq * (1.f / E) - mean * mean, 0.f);
  float rstd = rsqrtf(var + 1e-3f);
#pragma unroll
  for (int j = 0; j < 2; ++j) {
    int e = t + j * 256;
    outp[(size_t)r * E + e] = (v[j] - mean) * rstd * g[e] + bb[e];
  }
}

}  // namespace

extern "C" void kernel_launch(void* const* d_in, const int* in_sizes, int n_in,
                              void* d_out, int out_size, void* d_ws, size_t ws_size,
                              hipStream_t stream) {
  const float* x = (const float*)d_in[0];
  const float* wq = (const float*)d_in[1];
  const float* wk = (const float*)d_in[2];
  const float* wv = (const float*)d_in[3];
  const float* ln0_g = (const float*)d_in[4];
  const float* ln0_b = (const float*)d_in[5];
  const float* w1 = (const float*)d_in[6];
  const float* b1 = (const float*)d_in[7];
  const float* w2 = (const float*)d_in[8];
  const float* b2 = (const float*)d_in[9];
  const float* ln1_g = (const float*)d_in[10];
  const float* ln1_b = (const float*)d_in[11];

  float* att_out = (float*)d_out;                        // [B,S,H]
  float* outp = (float*)d_out + (size_t)B * S * H;       // [B,S,E]

  char* ws = (char*)d_ws;
  float* xsum = (float*)(ws);                            // 64 KB
  float* wqkb = (float*)(ws + 65536);                    // 512 KB
  float* scores = (float*)(ws + 589824);                 // 512 KB
  float* attw = (float*)(ws + 1114112);                  // 512 KB
  float* sqnorm = (float*)(ws + 1638400);                // 256 B
  float* rinv = (float*)(ws + 1638656);                  // 64 KB
  float* headout = (float*)(ws + 2097152);               // 32 MB [B,H,S,P]
  float* hbuf = (float*)(ws + 35651584);                 // 32 MB [BS,E]
  unsigned short* p1 = (unsigned short*)(ws + 69206016); // 48 MB bf16 [BS,FF]
  float* p2r = headout;                                  // reuse (headout dead after LN0)

  hipMemsetAsync(xsum, 0, (size_t)B * E * sizeof(float), stream);
  hipMemsetAsync(sqnorm, 0, 256, stream);

  k_xsum<<<dim3(B, 8), 256, 0, stream>>>(x, xsum);
  k_wqk<<<dim3(B, H), 64, 0, stream>>>(xsum, wq, wk, wqkb);
  k_scores<<<dim3(B, S / 64), 256, 0, stream>>>(x, wqkb, scores);
  k_softmax<<<B * H, 256, 0, stream>>>(scores, attw, att_out);
  k_vproj<<<dim3(B * H, S / 64), 256, 0, stream>>>(x, wv, attw, headout, sqnorm);
  k_ln0<<<BS, 256, 0, stream>>>(headout, x, sqnorm, ln0_g, ln0_b, hbuf);
  k_ffn1<<<dim3(BS / 64, FF / 64), 256, 0, stream>>>(hbuf, w1, b1, p1);
  k_rownorm<<<BS, 256, 0, stream>>>((const unsigned int*)p1, rinv);
  k_ffn2<<<dim3(BS / 64, E / 64), 256, 0, stream>>>(p1, w2, rinv, b2, hbuf, p2r);
  k_ln1<<<BS, 256, 0, stream>>>(p2r, ln1_g, ln1_b, outp);
}

// Round 2
// 228.315 us; speedup vs baseline: 3.7769x; 3.7769x over previous
//
#include <hip/hip_runtime.h>
#include <hip/hip_bf16.h>

namespace {

constexpr int B = 32, S = 512, E = 512, H = 8, P = 64, FF = 1536;
constexpr int BS = B * S;

typedef short v8s __attribute__((ext_vector_type(8)));
typedef float v4f __attribute__((ext_vector_type(4)));

__device__ __forceinline__ float bf2f(unsigned short u) {
  return __uint_as_float(((unsigned int)u) << 16);
}
__device__ __forceinline__ unsigned short f2bf(float f) {
  __hip_bfloat16 h = __float2bfloat16(f);
  return *reinterpret_cast<unsigned short*>(&h);
}

// ---------------- small kernels (unchanged structure) ----------------

__global__ __launch_bounds__(256) void k_xsum(const float* __restrict__ x, float* __restrict__ xsum) {
  int b = blockIdx.x, ch = blockIdx.y, t = threadIdx.x;
  const float* xp = x + ((size_t)b * S + ch * 64) * E;
  float a0 = 0.f, a1 = 0.f;
  for (int s = 0; s < 64; ++s) {
    a0 += xp[(size_t)s * E + t];
    a1 += xp[(size_t)s * E + t + 256];
  }
  atomicAdd(&xsum[b * E + t], a0);
  atomicAdd(&xsum[b * E + t + 256], a1);
}

__global__ __launch_bounds__(64) void k_wqk(const float* __restrict__ xsum, const float* __restrict__ wq,
                                            const float* __restrict__ wk, float* __restrict__ wqk) {
  int b = blockIdx.x, h = blockIdx.y;
  int p = threadIdx.x;
  __shared__ float ks[P];
  const float* wkh = wk + (size_t)h * E * P;
  const float* xs = xsum + b * E;
  float acc = 0.f;
  for (int e = 0; e < E; ++e) acc += xs[e] * wkh[e * P + p];
  ks[p] = acc;
  __syncthreads();
  const float* wqh = wq + (size_t)h * E * P;
  for (int k = 0; k < E / 64; ++k) {
    int e = threadIdx.x + k * 64;
    float a = 0.f;
#pragma unroll 8
    for (int pp = 0; pp < P; ++pp) a += wqh[e * P + pp] * ks[pp];
    wqk[((size_t)b * H + h) * E + e] = a * 0.125f;
  }
}

__global__ __launch_bounds__(256) void k_scores(const float* __restrict__ x, const float* __restrict__ wqk,
                                                float* __restrict__ scores) {
  int b = blockIdx.x, s0 = blockIdx.y * 64, t = threadIdx.x;
  __shared__ float xs[64][68];
  __shared__ float wt[8][68];
  float acc[2] = {0.f, 0.f};
  for (int ec = 0; ec < E; ec += 64) {
#pragma unroll
    for (int j = 0; j < 4; ++j) {
      int i = t + j * 256;
      int row = i >> 4, c4 = i & 15;
      float4 v = *(const float4*)(x + ((size_t)b * S + s0 + row) * E + ec + c4 * 4);
      *(float4*)&xs[row][c4 * 4] = v;
    }
    if (t < 128) {
      int hr = t >> 4, c4 = t & 15;
      float4 v = *(const float4*)(wqk + ((size_t)b * H + hr) * E + ec + c4 * 4);
      *(float4*)&wt[hr][c4 * 4] = v;
    }
    __syncthreads();
#pragma unroll
    for (int j = 0; j < 2; ++j) {
      int o = t + j * 256;
      int sl = o >> 3, hh = o & 7;
      float a = 0.f;
#pragma unroll
      for (int c4 = 0; c4 < 16; ++c4) {
        float4 xa = *(const float4*)&xs[sl][c4 * 4];
        float4 wa = *(const float4*)&wt[hh][c4 * 4];
        a += xa.x * wa.x + xa.y * wa.y + xa.z * wa.z + xa.w * wa.w;
      }
      acc[j] += a;
    }
    __syncthreads();
  }
#pragma unroll
  for (int j = 0; j < 2; ++j) {
    int o = t + j * 256;
    int sl = o >> 3, hh = o & 7;
    scores[((size_t)b * H + hh) * S + s0 + sl] = acc[j];
  }
}

__global__ __launch_bounds__(256) void k_softmax(const float* __restrict__ scores, float* __restrict__ attw,
                                                 float* __restrict__ att_out) {
  int bh = blockIdx.x, t = threadIdx.x;
  int b = bh >> 3, h = bh & 7;
  float v0 = scores[(size_t)bh * S + t];
  float v1 = scores[(size_t)bh * S + t + 256];
  float m = fmaxf(v0, v1);
#pragma unroll
  for (int off = 32; off; off >>= 1) m = fmaxf(m, __shfl_xor(m, off));
  __shared__ float rm[4], rs[4];
  if ((t & 63) == 0) rm[t >> 6] = m;
  __syncthreads();
  m = fmaxf(fmaxf(rm[0], rm[1]), fmaxf(rm[2], rm[3]));
  float e0 = __expf(v0 - m), e1 = __expf(v1 - m);
  float sm = e0 + e1;
#pragma unroll
  for (int off = 32; off; off >>= 1) sm += __shfl_xor(sm, off);
  if ((t & 63) == 0) rs[t >> 6] = sm;
  __syncthreads();
  float inv = 1.f / (rs[0] + rs[1] + rs[2] + rs[3]);
  float a0 = e0 * inv, a1 = e1 * inv;
  attw[(size_t)bh * S + t] = a0;
  attw[(size_t)bh * S + t + 256] = a1;
  att_out[((size_t)b * S + t) * H + h] = a0;
  att_out[((size_t)b * S + t + 256) * H + h] = a1;
}

// transpose+convert: in [R][C] f32 (at +z*R*C) -> out [C][R] bf16 (at +z*R*C)
__global__ __launch_bounds__(256) void k_trcvt(const float* __restrict__ inp, unsigned short* __restrict__ outp,
                                               int R, int C) {
  int c0 = blockIdx.x * 64, r0 = blockIdx.y * 64;
  size_t zo = (size_t)blockIdx.z * R * C;
  __shared__ float tile[64][65];
  int t = threadIdx.x;
#pragma unroll
  for (int j = 0; j < 4; ++j) {
    int i = t + j * 256;
    int rr = i >> 4, c4 = i & 15;
    float4 v = *(const float4*)(inp + zo + (size_t)(r0 + rr) * C + c0 + c4 * 4);
    tile[rr][c4 * 4 + 0] = v.x;
    tile[rr][c4 * 4 + 1] = v.y;
    tile[rr][c4 * 4 + 2] = v.z;
    tile[rr][c4 * 4 + 3] = v.w;
  }
  __syncthreads();
#pragma unroll
  for (int j = 0; j < 4; ++j) {
    int u = t + j * 256;
    int cr = u >> 4, q = u & 15;
    ushort4 o;
    o.x = f2bf(tile[q * 4 + 0][cr]);
    o.y = f2bf(tile[q * 4 + 1][cr]);
    o.z = f2bf(tile[q * 4 + 2][cr]);
    o.w = f2bf(tile[q * 4 + 3][cr]);
    *(ushort4*)(outp + zo + (size_t)(c0 + cr) * R + r0 + q * 4) = o;
  }
}

// ---------------- MFMA GEMM core: C[128x128] = A[M,K] x Bt[N,K]^T ----------------
// 4 waves (2x2), each wave 64x64 via 4x4 frags of 16x16x32 bf16 MFMA.
template <int KD, bool AF32>
__device__ __forceinline__ void gemm_tile(const void* __restrict__ Ap, const unsigned short* __restrict__ Bt,
                                          int lda, int ldb, int m0, int n0,
                                          unsigned short* As, unsigned short* Bs, v4f acc[4][4]) {
  const int t = threadIdx.x;
  const int l = t & 63, w = t >> 6;
  const int wr = w >> 1, wc = w & 1;
  const int u0 = t, u1 = t + 256;
  auto ldA = [&](int u, int kc) -> v8s {
    if constexpr (AF32) {
      const float* a = (const float*)Ap + (size_t)(m0 + (u >> 2)) * lda + kc + (u & 3) * 8;
      float4 x0 = *(const float4*)a;
      float4 x1 = *(const float4*)(a + 4);
      v8s r;
      r[0] = (short)f2bf(x0.x); r[1] = (short)f2bf(x0.y); r[2] = (short)f2bf(x0.z); r[3] = (short)f2bf(x0.w);
      r[4] = (short)f2bf(x1.x); r[5] = (short)f2bf(x1.y); r[6] = (short)f2bf(x1.z); r[7] = (short)f2bf(x1.w);
      return r;
    } else {
      return *(const v8s*)((const unsigned short*)Ap + (size_t)(m0 + (u >> 2)) * lda + kc + (u & 3) * 8);
    }
  };
  auto ldB = [&](int u, int kc) -> v8s {
    return *(const v8s*)(Bt + (size_t)(n0 + (u >> 2)) * ldb + kc + (u & 3) * 8);
  };
  v8s ra0 = ldA(u0, 0), ra1 = ldA(u1, 0), rb0 = ldB(u0, 0), rb1 = ldB(u1, 0);
  for (int kc = 0; kc < KD; kc += 32) {
    __syncthreads();
    *(v8s*)(As + (u0 >> 2) * 32 + (u0 & 3) * 8) = ra0;
    *(v8s*)(As + (u1 >> 2) * 32 + (u1 & 3) * 8) = ra1;
    *(v8s*)(Bs + (u0 >> 2) * 32 + (u0 & 3) * 8) = rb0;
    *(v8s*)(Bs + (u1 >> 2) * 32 + (u1 & 3) * 8) = rb1;
    __syncthreads();
    if (kc + 32 < KD) {
      ra0 = ldA(u0, kc + 32); ra1 = ldA(u1, kc + 32);
      rb0 = ldB(u0, kc + 32); rb1 = ldB(u1, kc + 32);
    }
    const int ch = l >> 4, r15 = l & 15;
    v8s af[4], bfr[4];
#pragma unroll
    for (int i = 0; i < 4; ++i) {
      af[i] = *(const v8s*)(As + (wr * 64 + i * 16 + r15) * 32 + ch * 8);
      bfr[i] = *(const v8s*)(Bs + (wc * 64 + i * 16 + r15) * 32 + ch * 8);
    }
#pragma unroll
    for (int i = 0; i < 4; ++i)
#pragma unroll
      for (int j = 0; j < 4; ++j)
        acc[i][j] = __builtin_amdgcn_mfma_f32_16x16x32_bf16(af[i], bfr[j], acc[i][j], 0, 0, 0);
  }
}

// V-projection GEMM: vb[(b,s)][h*64+p] = bf16((x @ wv)*attw); sqnorm[h] += sum o^2
__global__ __launch_bounds__(256) void k_gemm_v(const float* __restrict__ x, const unsigned short* __restrict__ wvt,
                                                const float* __restrict__ attw, unsigned short* __restrict__ vb,
                                                float* __restrict__ sqnorm) {
  __shared__ unsigned short As[4096], Bs[4096];
  int m0 = blockIdx.x * 128, n0 = blockIdx.y * 128;
  v4f acc[4][4] = {};
  gemm_tile<512, true>(x, wvt, 512, 512, m0, n0, As, Bs, acc);
  int t = threadIdx.x, l = t & 63, w = t >> 6, wr = w >> 1, wc = w & 1;
  int h = blockIdx.y * 2 + wc;
  float ssq = 0.f;
#pragma unroll
  for (int i = 0; i < 4; ++i) {
#pragma unroll
    for (int q = 0; q < 4; ++q) {
      int row = m0 + wr * 64 + i * 16 + (l >> 4) * 4 + q;
      int b = row >> 9, s = row & 511;
      float aw = attw[(size_t)(b * 8 + h) * 512 + s];
#pragma unroll
      for (int j = 0; j < 4; ++j) {
        int gc = n0 + wc * 64 + j * 16 + (l & 15);
        float o = acc[i][j][q] * aw;
        ssq += o * o;
        vb[(size_t)row * 512 + gc] = f2bf(o);
      }
    }
  }
#pragma unroll
  for (int off = 32; off; off >>= 1) ssq += __shfl_xor(ssq, off);
  if (l == 0) atomicAdd(&sqnorm[h], ssq);
}

// LN0: h = LN(merged + x); merged[e=p*8+h] = vb[col=h*64+p]*rsqrt(sqnorm[h])
__global__ __launch_bounds__(256) void k_ln0(const unsigned short* __restrict__ vb, const float* __restrict__ x,
                                             const float* __restrict__ sqnorm, const float* __restrict__ g,
                                             const float* __restrict__ bb, float* __restrict__ hbuf,
                                             unsigned short* __restrict__ hb) {
  int r = blockIdx.x, t = threadIdx.x;
  float hs = rsqrtf(fmaxf(sqnorm[t & 7], 1e-12f));
  float v[2];
#pragma unroll
  for (int j = 0; j < 2; ++j) {
    int e = t + j * 256;
    int col = (e & 7) * 64 + (e >> 3);
    v[j] = bf2f(vb[(size_t)r * 512 + col]) * hs + x[(size_t)r * 512 + e];
  }
  float sum = v[0] + v[1];
  float sq = v[0] * v[0] + v[1] * v[1];
#pragma unroll
  for (int off = 32; off; off >>= 1) {
    sum += __shfl_xor(sum, off);
    sq += __shfl_xor(sq, off);
  }
  __shared__ float r0[4], r1[4];
  if ((t & 63) == 0) { r0[t >> 6] = sum; r1[t >> 6] = sq; }
  __syncthreads();
  sum = r0[0] + r0[1] + r0[2] + r0[3];
  sq = r1[0] + r1[1] + r1[2] + r1[3];
  float mean = sum * (1.f / E);
  float var = fmaxf(sq * (1.f / E) - mean * mean, 0.f);
  float rstd = rsqrtf(var + 1e-3f);
#pragma unroll
  for (int j = 0; j < 2; ++j) {
    int e = t + j * 256;
    float o = (v[j] - mean) * rstd * g[e] + bb[e];
    hbuf[(size_t)r * E + e] = o;
    hb[(size_t)r * E + e] = f2bf(o);
  }
}

// FFN1: p1 = bf16(leaky_relu(hb @ w1 + b1))
__global__ __launch_bounds__(256) void k_ffn1(const unsigned short* __restrict__ hb,
                                              const unsigned short* __restrict__ w1t,
                                              const float* __restrict__ b1, unsigned short* __restrict__ p1) {
  __shared__ unsigned short As[4096], Bs[4096];
  int m0 = blockIdx.x * 128, n0 = blockIdx.y * 128;
  v4f acc[4][4] = {};
  gemm_tile<512, false>(hb, w1t, 512, 512, m0, n0, As, Bs, acc);
  int t = threadIdx.x, l = t & 63, w = t >> 6, wr = w >> 1, wc = w & 1;
  int colb = n0 + wc * 64 + (l & 15);
  float bias[4];
#pragma unroll
  for (int j = 0; j < 4; ++j) bias[j] = b1[colb + j * 16];
#pragma unroll
  for (int i = 0; i < 4; ++i)
#pragma unroll
    for (int q = 0; q < 4; ++q) {
      int row = m0 + wr * 64 + i * 16 + (l >> 4) * 4 + q;
#pragma unroll
      for (int j = 0; j < 4; ++j) {
        float v = acc[i][j][q] + bias[j];
        v = v > 0.f ? v : 0.2f * v;
        p1[(size_t)row * FF + colb + j * 16] = f2bf(v);
      }
    }
}

__global__ __launch_bounds__(256) void k_rownorm(const unsigned int* __restrict__ p1u, float* __restrict__ rinv) {
  int r = blockIdx.x, t = threadIdx.x;
  const unsigned int* row = p1u + (size_t)r * (FF / 2);
  float ss = 0.f;
#pragma unroll
  for (int j = 0; j < 3; ++j) {
    unsigned int u = row[t + j * 256];
    float lo = __uint_as_float(u << 16);
    float hi = __uint_as_float(u & 0xffff0000u);
    ss += lo * lo + hi * hi;
  }
#pragma unroll
  for (int off = 32; off; off >>= 1) ss += __shfl_xor(ss, off);
  __shared__ float rs[4];
  if ((t & 63) == 0) rs[t >> 6] = ss;
  __syncthreads();
  if (t == 0) rinv[r] = rsqrtf(fmaxf(rs[0] + rs[1] + rs[2] + rs[3], 1e-12f));
}

// FFN2 (in-place): hbuf = (p1 @ w2)*rinv + b2 + hbuf
__global__ __launch_bounds__(256) void k_ffn2(const unsigned short* __restrict__ p1,
                                              const unsigned short* __restrict__ w2t,
                                              const float* __restrict__ rinv, const float* __restrict__ b2,
                                              float* __restrict__ hbuf) {
  __shared__ unsigned short As[4096], Bs[4096];
  int m0 = blockIdx.x * 128, n0 = blockIdx.y * 128;
  v4f acc[4][4] = {};
  gemm_tile<1536, false>(p1, w2t, 1536, 1536, m0, n0, As, Bs, acc);
  int t = threadIdx.x, l = t & 63, w = t >> 6, wr = w >> 1, wc = w & 1;
  int colb = n0 + wc * 64 + (l & 15);
  float bias[4];
#pragma unroll
  for (int j = 0; j < 4; ++j) bias[j] = b2[colb + j * 16];
#pragma unroll
  for (int i = 0; i < 4; ++i)
#pragma unroll
    for (int q = 0; q < 4; ++q) {
      int row = m0 + wr * 64 + i * 16 + (l >> 4) * 4 + q;
      float rv = rinv[row];
#pragma unroll
      for (int j = 0; j < 4; ++j) {
        size_t idx = (size_t)row * 512 + colb + j * 16;
        hbuf[idx] = acc[i][j][q] * rv + bias[j] + hbuf[idx];
      }
    }
}

__global__ __launch_bounds__(256) void k_ln1(const float* __restrict__ p2r, const float* __restrict__ g,
                                             const float* __restrict__ bb, float* __restrict__ outp) {
  int r = blockIdx.x, t = threadIdx.x;
  float v[2];
#pragma unroll
  for (int j = 0; j < 2; ++j) v[j] = p2r[(size_t)r * E + t + j * 256];
  float sum = v[0] + v[1];
  float sq = v[0] * v[0] + v[1] * v[1];
#pragma unroll
  for (int off = 32; off; off >>= 1) {
    sum += __shfl_xor(sum, off);
    sq += __shfl_xor(sq, off);
  }
  __shared__ float r0[4], r1[4];
  if ((t & 63) == 0) { r0[t >> 6] = sum; r1[t >> 6] = sq; }
  __syncthreads();
  sum = r0[0] + r0[1] + r0[2] + r0[3];
  sq = r1[0] + r1[1] + r1[2] + r1[3];
  float mean = sum * (1.f / E);
  float var = fmaxf(sq * (1.f / E) - mean * mean, 0.f);
  float rstd = rsqrtf(var + 1e-3f);
#pragma unroll
  for (int j = 0; j < 2; ++j) {
    int e = t + j * 256;
    outp[(size_t)r * E + e] = (v[j] - mean) * rstd * g[e] + bb[e];
  }
}

}  // namespace

extern "C" void kernel_launch(void* const* d_in, const int* in_sizes, int n_in,
                              void* d_out, int out_size, void* d_ws, size_t ws_size,
                              hipStream_t stream) {
  const float* x = (const float*)d_in[0];
  const float* wq = (const float*)d_in[1];
  const float* wk = (const float*)d_in[2];
  const float* wv = (const float*)d_in[3];
  const float* ln0_g = (const float*)d_in[4];
  const float* ln0_b = (const float*)d_in[5];
  const float* w1 = (const float*)d_in[6];
  const float* b1 = (const float*)d_in[7];
  const float* w2 = (const float*)d_in[8];
  const float* b2 = (const float*)d_in[9];
  const float* ln1_g = (const float*)d_in[10];
  const float* ln1_b = (const float*)d_in[11];

  float* att_out = (float*)d_out;                  // [B,S,H]
  float* outp = (float*)d_out + (size_t)B * S * H; // [B,S,E]

  char* ws = (char*)d_ws;
  float* xsum = (float*)(ws + 0);                       // 64 KB
  float* wqkb = (float*)(ws + 65536);                   // 512 KB
  float* scores = (float*)(ws + 589824);                // 512 KB
  float* attw = (float*)(ws + 1114112);                 // 512 KB
  float* sqnorm = (float*)(ws + 1638400);               // 256 B
  float* rinv = (float*)(ws + 1638656);                 // 64 KB
  unsigned short* w1t = (unsigned short*)(ws + 1704192);  // 1.5 MB  [FF][E]
  unsigned short* w2t = (unsigned short*)(ws + 3277056);  // 1.5 MB  [E][FF]
  unsigned short* wvt = (unsigned short*)(ws + 4849920);  // 0.5 MB  [H*P][E]
  unsigned short* vb = (unsigned short*)(ws + 5374208);   // 16 MB   [BS][512] bf16
  float* hbuf = (float*)(ws + 22151424);                  // 32 MB   [BS][E] f32 (also p2r, in-place)
  unsigned short* hb = (unsigned short*)(ws + 55705856);  // 16 MB   [BS][E] bf16
  unsigned short* p1 = (unsigned short*)(ws + 72483072);  // 48 MB   [BS][FF] bf16

  hipMemsetAsync(xsum, 0, (size_t)B * E * sizeof(float), stream);
  hipMemsetAsync(sqnorm, 0, 256, stream);

  // weight prep (bf16 transposed [N][K] operands)
  k_trcvt<<<dim3(FF / 64, E / 64, 1), 256, 0, stream>>>(w1, w1t, E, FF);
  k_trcvt<<<dim3(E / 64, FF / 64, 1), 256, 0, stream>>>(w2, w2t, FF, E);
  k_trcvt<<<dim3(1, E / 64, H), 256, 0, stream>>>(wv, wvt, E, P);

  k_xsum<<<dim3(B, 8), 256, 0, stream>>>(x, xsum);
  k_wqk<<<dim3(B, H), 64, 0, stream>>>(xsum, wq, wk, wqkb);
  k_scores<<<dim3(B, S / 64), 256, 0, stream>>>(x, wqkb, scores);
  k_softmax<<<B * H, 256, 0, stream>>>(scores, attw, att_out);
  k_gemm_v<<<dim3(BS / 128, 4), 256, 0, stream>>>(x, wvt, attw, vb, sqnorm);
  k_ln0<<<BS, 256, 0, stream>>>(vb, x, sqnorm, ln0_g, ln0_b, hbuf, hb);
  k_ffn1<<<dim3(BS / 128, FF / 128), 256, 0, stream>>>(hb, w1t, b1, p1);
  k_rownorm<<<BS, 256, 0, stream>>>((const unsigned int*)p1, rinv);
  k_ffn2<<<dim3(BS / 128, E / 128), 256, 0, stream>>>(p1, w2t, rinv, b2, hbuf);
  k_ln1<<<BS, 256, 0, stream>>>(hbuf, ln1_g, ln1_b, outp);
}

// Round 3
// 209.977 us; speedup vs baseline: 4.1068x; 1.0873x over previous
//
#include <hip/hip_runtime.h>
#include <hip/hip_bf16.h>

namespace {

constexpr int B = 32, S = 512, E = 512, H = 8, P = 64, FF = 1536;
constexpr int BS = B * S;

typedef short v8s __attribute__((ext_vector_type(8)));
typedef float v4f __attribute__((ext_vector_type(4)));

__device__ __forceinline__ float bf2f(unsigned short u) {
  return __uint_as_float(((unsigned int)u) << 16);
}
__device__ __forceinline__ unsigned short f2bf(float f) {
  __hip_bfloat16 h = __float2bfloat16(f);
  return *reinterpret_cast<unsigned short*>(&h);
}

__device__ __forceinline__ void gl_lds16(const unsigned short* g, unsigned short* l) {
  __builtin_amdgcn_global_load_lds((const __attribute__((address_space(1))) unsigned int*)g,
                                   (__attribute__((address_space(3))) unsigned int*)l, 16, 0, 0);
}

// ---------------- x -> bf16 convert + per-batch column sum ----------------
// grid (B, 8) x 256: block covers 64 rows of batch b.
__global__ __launch_bounds__(256) void k_xcvt(const float* __restrict__ x, unsigned short* __restrict__ xb,
                                              float* __restrict__ xsum) {
  int b = blockIdx.x, ch = blockIdx.y, t = threadIdx.x;
  int c4 = (t & 127) * 4;
  int rh = t >> 7;
  const float* xp = x + ((size_t)b * S + ch * 64 + rh * 32) * E;
  unsigned short* xbp = xb + ((size_t)b * S + ch * 64 + rh * 32) * E;
  float ax = 0.f, ay = 0.f, az = 0.f, aw = 0.f;
  for (int s = 0; s < 32; ++s) {
    float4 v = *(const float4*)(xp + (size_t)s * E + c4);
    ax += v.x; ay += v.y; az += v.z; aw += v.w;
    ushort4 u;
    u.x = f2bf(v.x); u.y = f2bf(v.y); u.z = f2bf(v.z); u.w = f2bf(v.w);
    *(ushort4*)(xbp + (size_t)s * E + c4) = u;
  }
  float* xs = xsum + b * E + c4;
  atomicAdd(xs + 0, ax);
  atomicAdd(xs + 1, ay);
  atomicAdd(xs + 2, az);
  atomicAdd(xs + 3, aw);
}

__global__ __launch_bounds__(64) void k_wqk(const float* __restrict__ xsum, const float* __restrict__ wq,
                                            const float* __restrict__ wk, float* __restrict__ wqk) {
  int b = blockIdx.x, h = blockIdx.y;
  int p = threadIdx.x;
  __shared__ float ks[P];
  const float* wkh = wk + (size_t)h * E * P;
  const float* xs = xsum + b * E;
  float acc = 0.f;
  for (int e = 0; e < E; ++e) acc += xs[e] * wkh[e * P + p];
  ks[p] = acc;
  __syncthreads();
  const float* wqh = wq + (size_t)h * E * P;
  for (int k = 0; k < E / 64; ++k) {
    int e = threadIdx.x + k * 64;
    float a = 0.f;
#pragma unroll 8
    for (int pp = 0; pp < P; ++pp) a += wqh[e * P + pp] * ks[pp];
    wqk[((size_t)b * H + h) * E + e] = a * 0.125f;
  }
}

__global__ __launch_bounds__(256) void k_scores(const float* __restrict__ x, const float* __restrict__ wqk,
                                                float* __restrict__ scores) {
  int b = blockIdx.x, s0 = blockIdx.y * 64, t = threadIdx.x;
  __shared__ float xs[64][68];
  __shared__ float wt[8][68];
  float acc[2] = {0.f, 0.f};
  for (int ec = 0; ec < E; ec += 64) {
#pragma unroll
    for (int j = 0; j < 4; ++j) {
      int i = t + j * 256;
      int row = i >> 4, c4 = i & 15;
      float4 v = *(const float4*)(x + ((size_t)b * S + s0 + row) * E + ec + c4 * 4);
      *(float4*)&xs[row][c4 * 4] = v;
    }
    if (t < 128) {
      int hr = t >> 4, c4 = t & 15;
      float4 v = *(const float4*)(wqk + ((size_t)b * H + hr) * E + ec + c4 * 4);
      *(float4*)&wt[hr][c4 * 4] = v;
    }
    __syncthreads();
#pragma unroll
    for (int j = 0; j < 2; ++j) {
      int o = t + j * 256;
      int sl = o >> 3, hh = o & 7;
      float a = 0.f;
#pragma unroll
      for (int c4 = 0; c4 < 16; ++c4) {
        float4 xa = *(const float4*)&xs[sl][c4 * 4];
        float4 wa = *(const float4*)&wt[hh][c4 * 4];
        a += xa.x * wa.x + xa.y * wa.y + xa.z * wa.z + xa.w * wa.w;
      }
      acc[j] += a;
    }
    __syncthreads();
  }
#pragma unroll
  for (int j = 0; j < 2; ++j) {
    int o = t + j * 256;
    int sl = o >> 3, hh = o & 7;
    scores[((size_t)b * H + hh) * S + s0 + sl] = acc[j];
  }
}

__global__ __launch_bounds__(256) void k_softmax(const float* __restrict__ scores, float* __restrict__ attw,
                                                 float* __restrict__ att_out) {
  int bh = blockIdx.x, t = threadIdx.x;
  int b = bh >> 3, h = bh & 7;
  float v0 = scores[(size_t)bh * S + t];
  float v1 = scores[(size_t)bh * S + t + 256];
  float m = fmaxf(v0, v1);
#pragma unroll
  for (int off = 32; off; off >>= 1) m = fmaxf(m, __shfl_xor(m, off));
  __shared__ float rm[4], rs[4];
  if ((t & 63) == 0) rm[t >> 6] = m;
  __syncthreads();
  m = fmaxf(fmaxf(rm[0], rm[1]), fmaxf(rm[2], rm[3]));
  float e0 = __expf(v0 - m), e1 = __expf(v1 - m);
  float sm = e0 + e1;
#pragma unroll
  for (int off = 32; off; off >>= 1) sm += __shfl_xor(sm, off);
  if ((t & 63) == 0) rs[t >> 6] = sm;
  __syncthreads();
  float inv = 1.f / (rs[0] + rs[1] + rs[2] + rs[3]);
  float a0 = e0 * inv, a1 = e1 * inv;
  attw[(size_t)bh * S + t] = a0;
  attw[(size_t)bh * S + t + 256] = a1;
  att_out[((size_t)b * S + t) * H + h] = a0;
  att_out[((size_t)b * S + t + 256) * H + h] = a1;
}

// transpose+convert: in [R][C] f32 (at +z*R*C) -> out [C][R] bf16 (at +z*R*C)
__global__ __launch_bounds__(256) void k_trcvt(const float* __restrict__ inp, unsigned short* __restrict__ outp,
                                               int R, int C) {
  int c0 = blockIdx.x * 64, r0 = blockIdx.y * 64;
  size_t zo = (size_t)blockIdx.z * R * C;
  __shared__ float tile[64][65];
  int t = threadIdx.x;
#pragma unroll
  for (int j = 0; j < 4; ++j) {
    int i = t + j * 256;
    int rr = i >> 4, c4 = i & 15;
    float4 v = *(const float4*)(inp + zo + (size_t)(r0 + rr) * C + c0 + c4 * 4);
    tile[rr][c4 * 4 + 0] = v.x;
    tile[rr][c4 * 4 + 1] = v.y;
    tile[rr][c4 * 4 + 2] = v.z;
    tile[rr][c4 * 4 + 3] = v.w;
  }
  __syncthreads();
#pragma unroll
  for (int j = 0; j < 4; ++j) {
    int u = t + j * 256;
    int cr = u >> 4, q = u & 15;
    ushort4 o;
    o.x = f2bf(tile[q * 4 + 0][cr]);
    o.y = f2bf(tile[q * 4 + 1][cr]);
    o.z = f2bf(tile[q * 4 + 2][cr]);
    o.w = f2bf(tile[q * 4 + 3][cr]);
    *(ushort4*)(outp + zo + (size_t)(c0 + cr) * R + r0 + q * 4) = o;
  }
}

// ---------------- MFMA GEMM core (m97 structure): global_load_lds w16, single LDS buf,
// 2 barriers/K-step, granule swizzle g^=(row>>1)&3 (inverse-swz source + swz read).
template <int KD>
__device__ __forceinline__ void gemm_tile_gl(const unsigned short* __restrict__ A,
                                             const unsigned short* __restrict__ Bt,
                                             int lda, int ldb, int m0, int n0,
                                             unsigned short* As, unsigned short* Bs, v4f acc[4][4]) {
  const int t = threadIdx.x;
  const int l = t & 63, w = t >> 6;
  const int wr = w >> 1, wc = w & 1;
  const int lr = l >> 2, lg = l & 3;
  const int ch = l >> 4, r15 = l & 15;
  for (int kc = 0; kc < KD; kc += 32) {
#pragma unroll
    for (int cc = 0; cc < 2; ++cc) {
      int c = w * 2 + cc;
      int row = c * 16 + lr;
      int sg = lg ^ ((row >> 1) & 3);  // inverse-swizzled source granule
      const unsigned short* ga = A + (size_t)(m0 + row) * lda + kc + sg * 8;
      const unsigned short* gb = Bt + (size_t)(n0 + row) * ldb + kc + sg * 8;
      gl_lds16(ga, As + c * 512);
      gl_lds16(gb, Bs + c * 512);
    }
    __syncthreads();  // drains vmcnt: staged data visible
    v8s af[4], bfr[4];
#pragma unroll
    for (int i = 0; i < 4; ++i) {
      int ra = wr * 64 + i * 16 + r15;
      af[i] = *(const v8s*)(As + ra * 32 + (ch ^ ((ra >> 1) & 3)) * 8);
      int rb = wc * 64 + i * 16 + r15;
      bfr[i] = *(const v8s*)(Bs + rb * 32 + (ch ^ ((rb >> 1) & 3)) * 8);
    }
#pragma unroll
    for (int i = 0; i < 4; ++i)
#pragma unroll
      for (int j = 0; j < 4; ++j)
        acc[i][j] = __builtin_amdgcn_mfma_f32_16x16x32_bf16(af[i], bfr[j], acc[i][j], 0, 0, 0);
    __syncthreads();  // protect LDS before next stage
  }
}

// V-projection GEMM: vb[(b,s)][h*64+p] = bf16((xb @ wv)*attw); sqnorm[h] += sum o^2
__global__ __launch_bounds__(256) void k_gemm_v(const unsigned short* __restrict__ xb,
                                                const unsigned short* __restrict__ wvt,
                                                const float* __restrict__ attw, unsigned short* __restrict__ vb,
                                                float* __restrict__ sqnorm) {
  __shared__ alignas(16) unsigned short As[4096], Bs[4096];
  int m0 = blockIdx.x * 128, n0 = blockIdx.y * 128;
  v4f acc[4][4] = {};
  gemm_tile_gl<512>(xb, wvt, 512, 512, m0, n0, As, Bs, acc);
  int t = threadIdx.x, l = t & 63, w = t >> 6, wr = w >> 1, wc = w & 1;
  int h = blockIdx.y * 2 + wc;
  float ssq = 0.f;
#pragma unroll
  for (int i = 0; i < 4; ++i) {
#pragma unroll
    for (int q = 0; q < 4; ++q) {
      int row = m0 + wr * 64 + i * 16 + (l >> 4) * 4 + q;
      int b = row >> 9, s = row & 511;
      float aw = attw[(size_t)(b * 8 + h) * 512 + s];
#pragma unroll
      for (int j = 0; j < 4; ++j) {
        int gc = n0 + wc * 64 + j * 16 + (l & 15);
        float o = acc[i][j][q] * aw;
        ssq += o * o;
        vb[(size_t)row * 512 + gc] = f2bf(o);
      }
    }
  }
#pragma unroll
  for (int off = 32; off; off >>= 1) ssq += __shfl_xor(ssq, off);
  if (l == 0) atomicAdd(&sqnorm[h], ssq);
}

// LN0 (wave per row): h = LN(merged + x); merged[e=p*8+h] = vb[col=h*64+p]*rsqrt(sqnorm[h])
__global__ __launch_bounds__(256) void k_ln0(const unsigned short* __restrict__ vb,
                                             const unsigned short* __restrict__ xb,
                                             const float* __restrict__ sqnorm, const float* __restrict__ g,
                                             const float* __restrict__ bb, unsigned short* __restrict__ hb) {
  __shared__ unsigned short perm[4][512];
  int t = threadIdx.x, w = t >> 6, l = t & 63;
  int r = blockIdx.x * 4 + w;
  *(v8s*)&perm[w][l * 8] = *(const v8s*)(vb + (size_t)r * 512 + l * 8);
  __syncthreads();
  v8s xv = *(const v8s*)(xb + (size_t)r * 512 + l * 8);
  float v[8];
#pragma unroll
  for (int j = 0; j < 8; ++j) {
    float hs = rsqrtf(fmaxf(sqnorm[j], 1e-12f));
    v[j] = bf2f(perm[w][j * 64 + l]) * hs + bf2f((unsigned short)xv[j]);
  }
  float sum = 0.f, sq = 0.f;
#pragma unroll
  for (int j = 0; j < 8; ++j) { sum += v[j]; sq += v[j] * v[j]; }
#pragma unroll
  for (int off = 32; off; off >>= 1) {
    sum += __shfl_xor(sum, off);
    sq += __shfl_xor(sq, off);
  }
  float mean = sum * (1.f / E);
  float var = fmaxf(sq * (1.f / E) - mean * mean, 0.f);
  float rstd = rsqrtf(var + 1e-3f);
  float4 g0 = *(const float4*)(g + l * 8), g1 = *(const float4*)(g + l * 8 + 4);
  float4 b0 = *(const float4*)(bb + l * 8), b1 = *(const float4*)(bb + l * 8 + 4);
  float gg[8] = {g0.x, g0.y, g0.z, g0.w, g1.x, g1.y, g1.z, g1.w};
  float bbv[8] = {b0.x, b0.y, b0.z, b0.w, b1.x, b1.y, b1.z, b1.w};
  v8s hv;
#pragma unroll
  for (int j = 0; j < 8; ++j) hv[j] = (short)f2bf((v[j] - mean) * rstd * gg[j] + bbv[j]);
  *(v8s*)(hb + (size_t)r * 512 + l * 8) = hv;
}

// FFN1: p1 = bf16(leaky_relu(hb @ w1 + b1)); rsum[row] += sum_cols v^2
__global__ __launch_bounds__(256) void k_ffn1(const unsigned short* __restrict__ hb,
                                              const unsigned short* __restrict__ w1t,
                                              const float* __restrict__ b1, unsigned short* __restrict__ p1,
                                              float* __restrict__ rsum) {
  __shared__ alignas(16) unsigned short As[4096], Bs[4096];
  int m0 = blockIdx.x * 128, n0 = blockIdx.y * 128;
  v4f acc[4][4] = {};
  gemm_tile_gl<512>(hb, w1t, 512, 512, m0, n0, As, Bs, acc);
  int t = threadIdx.x, l = t & 63, w = t >> 6, wr = w >> 1, wc = w & 1;
  int colb = n0 + wc * 64 + (l & 15);
  float bias[4];
#pragma unroll
  for (int j = 0; j < 4; ++j) bias[j] = b1[colb + j * 16];
#pragma unroll
  for (int i = 0; i < 4; ++i) {
#pragma unroll
    for (int q = 0; q < 4; ++q) {
      int row = m0 + wr * 64 + i * 16 + (l >> 4) * 4 + q;
      float ps = 0.f;
#pragma unroll
      for (int j = 0; j < 4; ++j) {
        float v = acc[i][j][q] + bias[j];
        v = v > 0.f ? v : 0.2f * v;
        ps += v * v;
        p1[(size_t)row * FF + colb + j * 16] = f2bf(v);
      }
#pragma unroll
      for (int m = 1; m < 16; m <<= 1) ps += __shfl_xor(ps, m);
      if ((l & 15) == 0) atomicAdd(&rsum[row], ps);
    }
  }
}

__global__ __launch_bounds__(256) void k_rinv(const float* __restrict__ rsum, float* __restrict__ rinv) {
  int i = blockIdx.x * 256 + threadIdx.x;
  rinv[i] = rsqrtf(fmaxf(rsum[i], 1e-12f));
}

// FFN2: p2b = bf16((p1 @ w2)*rinv + b2 + hb)
__global__ __launch_bounds__(256) void k_ffn2(const unsigned short* __restrict__ p1,
                                              const unsigned short* __restrict__ w2t,
                                              const float* __restrict__ rinv, const float* __restrict__ b2,
                                              const unsigned short* __restrict__ hb,
                                              unsigned short* __restrict__ p2b) {
  __shared__ alignas(16) unsigned short As[4096], Bs[4096];
  int m0 = blockIdx.x * 128, n0 = blockIdx.y * 128;
  v4f acc[4][4] = {};
  gemm_tile_gl<1536>(p1, w2t, 1536, 1536, m0, n0, As, Bs, acc);
  int t = threadIdx.x, l = t & 63, w = t >> 6, wr = w >> 1, wc = w & 1;
  int colb = n0 + wc * 64 + (l & 15);
  float bias[4];
#pragma unroll
  for (int j = 0; j < 4; ++j) bias[j] = b2[colb + j * 16];
#pragma unroll
  for (int i = 0; i < 4; ++i) {
#pragma unroll
    for (int q = 0; q < 4; ++q) {
      int row = m0 + wr * 64 + i * 16 + (l >> 4) * 4 + q;
      float rv = rinv[row];
#pragma unroll
      for (int j = 0; j < 4; ++j) {
        size_t idx = (size_t)row * 512 + colb + j * 16;
        float o = acc[i][j][q] * rv + bias[j] + bf2f(hb[idx]);
        p2b[idx] = f2bf(o);
      }
    }
  }
}

// LN1 (wave per row): out = LN(p2b)
__global__ __launch_bounds__(256) void k_ln1(const unsigned short* __restrict__ p2b, const float* __restrict__ g,
                                             const float* __restrict__ bb, float* __restrict__ outp) {
  int t = threadIdx.x, w = t >> 6, l = t & 63;
  int r = blockIdx.x * 4 + w;
  v8s pv = *(const v8s*)(p2b + (size_t)r * 512 + l * 8);
  float v[8];
#pragma unroll
  for (int j = 0; j < 8; ++j) v[j] = bf2f((unsigned short)pv[j]);
  float sum = 0.f, sq = 0.f;
#pragma unroll
  for (int j = 0; j < 8; ++j) { sum += v[j]; sq += v[j] * v[j]; }
#pragma unroll
  for (int off = 32; off; off >>= 1) {
    sum += __shfl_xor(sum, off);
    sq += __shfl_xor(sq, off);
  }
  float mean = sum * (1.f / E);
  float var = fmaxf(sq * (1.f / E) - mean * mean, 0.f);
  float rstd = rsqrtf(var + 1e-3f);
  float4 g0 = *(const float4*)(g + l * 8), g1 = *(const float4*)(g + l * 8 + 4);
  float4 b0 = *(const float4*)(bb + l * 8), b1 = *(const float4*)(bb + l * 8 + 4);
  float gg[8] = {g0.x, g0.y, g0.z, g0.w, g1.x, g1.y, g1.z, g1.w};
  float bbv[8] = {b0.x, b0.y, b0.z, b0.w, b1.x, b1.y, b1.z, b1.w};
  float4 o0, o1;
  o0.x = (v[0] - mean) * rstd * gg[0] + bbv[0];
  o0.y = (v[1] - mean) * rstd * gg[1] + bbv[1];
  o0.z = (v[2] - mean) * rstd * gg[2] + bbv[2];
  o0.w = (v[3] - mean) * rstd * gg[3] + bbv[3];
  o1.x = (v[4] - mean) * rstd * gg[4] + bbv[4];
  o1.y = (v[5] - mean) * rstd * gg[5] + bbv[5];
  o1.z = (v[6] - mean) * rstd * gg[6] + bbv[6];
  o1.w = (v[7] - mean) * rstd * gg[7] + bbv[7];
  *(float4*)(outp + (size_t)r * 512 + l * 8) = o0;
  *(float4*)(outp + (size_t)r * 512 + l * 8 + 4) = o1;
}

}  // namespace

extern "C" void kernel_launch(void* const* d_in, const int* in_sizes, int n_in,
                              void* d_out, int out_size, void* d_ws, size_t ws_size,
                              hipStream_t stream) {
  const float* x = (const float*)d_in[0];
  const float* wq = (const float*)d_in[1];
  const float* wk = (const float*)d_in[2];
  const float* wv = (const float*)d_in[3];
  const float* ln0_g = (const float*)d_in[4];
  const float* ln0_b = (const float*)d_in[5];
  const float* w1 = (const float*)d_in[6];
  const float* b1 = (const float*)d_in[7];
  const float* w2 = (const float*)d_in[8];
  const float* b2 = (const float*)d_in[9];
  const float* ln1_g = (const float*)d_in[10];
  const float* ln1_b = (const float*)d_in[11];

  float* att_out = (float*)d_out;                  // [B,S,H]
  float* outp = (float*)d_out + (size_t)B * S * H; // [B,S,E]

  char* ws = (char*)d_ws;
  float* xsum = (float*)(ws + 0);                        // 64 KB
  float* wqkb = (float*)(ws + 65536);                    // 512 KB
  float* scores = (float*)(ws + 589824);                 // 512 KB
  float* attw = (float*)(ws + 1114112);                  // 512 KB
  float* sqnorm = (float*)(ws + 1638400);                // 256 B
  float* rsum = (float*)(ws + 1638656);                  // 64 KB
  float* rinv = (float*)(ws + 1704192);                  // 64 KB
  unsigned short* w1t = (unsigned short*)(ws + 1769728); // 1.5 MB [FF][E]
  unsigned short* w2t = (unsigned short*)(ws + 3342592); // 1.5 MB [E][FF]
  unsigned short* wvt = (unsigned short*)(ws + 4915456); // 0.5 MB [H*P][E]
  unsigned short* xb = (unsigned short*)(ws + 5439744);  // 16 MB [BS][E] bf16
  unsigned short* vb = (unsigned short*)(ws + 22216960); // 16 MB [BS][512] bf16 (p2b aliases)
  unsigned short* hb = (unsigned short*)(ws + 38994176); // 16 MB [BS][E] bf16
  unsigned short* p1 = (unsigned short*)(ws + 55771392); // 48 MB [BS][FF] bf16
  unsigned short* p2b = vb;                              // vb dead after ln0

  hipMemsetAsync(xsum, 0, (size_t)B * E * sizeof(float), stream);
  hipMemsetAsync(sqnorm, 0, 256, stream);
  hipMemsetAsync(rsum, 0, (size_t)BS * sizeof(float), stream);

  // weight prep (bf16 transposed [N][K] operands)
  k_trcvt<<<dim3(FF / 64, E / 64, 1), 256, 0, stream>>>(w1, w1t, E, FF);
  k_trcvt<<<dim3(E / 64, FF / 64, 1), 256, 0, stream>>>(w2, w2t, FF, E);
  k_trcvt<<<dim3(1, E / 64, H), 256, 0, stream>>>(wv, wvt, E, P);

  k_xcvt<<<dim3(B, 8), 256, 0, stream>>>(x, xb, xsum);
  k_wqk<<<dim3(B, H), 64, 0, stream>>>(xsum, wq, wk, wqkb);
  k_scores<<<dim3(B, S / 64), 256, 0, stream>>>(x, wqkb, scores);
  k_softmax<<<B * H, 256, 0, stream>>>(scores, attw, att_out);
  k_gemm_v<<<dim3(BS / 128, 4), 256, 0, stream>>>(xb, wvt, attw, vb, sqnorm);
  k_ln0<<<BS / 4, 256, 0, stream>>>(vb, xb, sqnorm, ln0_g, ln0_b, hb);
  k_ffn1<<<dim3(BS / 128, FF / 128), 256, 0, stream>>>(hb, w1t, b1, p1, rsum);
  k_rinv<<<BS / 256, 256, 0, stream>>>(rsum, rinv);
  k_ffn2<<<dim3(BS / 128, E / 128), 256, 0, stream>>>(p1, w2t, rinv, b2, hb, p2b);
  k_ln1<<<BS / 4, 256, 0, stream>>>(p2b, ln1_g, ln1_b, outp);
}

// Round 4
// 193.494 us; speedup vs baseline: 4.4566x; 1.0852x over previous
//
#include <hip/hip_runtime.h>
#include <hip/hip_bf16.h>

namespace {

constexpr int B = 32, S = 512, E = 512, H = 8, P = 64, FF = 1536;
constexpr int BS = B * S;

typedef short v8s __attribute__((ext_vector_type(8)));
typedef float v4f __attribute__((ext_vector_type(4)));

__device__ __forceinline__ float bf2f(unsigned short u) {
  return __uint_as_float(((unsigned int)u) << 16);
}
__device__ __forceinline__ unsigned short f2bf(float f) {
  __hip_bfloat16 h = __float2bfloat16(f);
  return *reinterpret_cast<unsigned short*>(&h);
}

__device__ __forceinline__ void gl_lds16(const unsigned short* g, unsigned short* l) {
  __builtin_amdgcn_global_load_lds((const __attribute__((address_space(1))) unsigned int*)g,
                                   (__attribute__((address_space(3))) unsigned int*)l, 16, 0, 0);
}

// ---------------- weight prep: one kernel for all three transposes ----------------
// w1 [E][FF] -> w1t [FF][E]; w2 [FF][E] -> w2t [E][FF]; wv [H][E][P] -> wvt [H][P][E]
__global__ __launch_bounds__(256) void k_wprep(const float* __restrict__ w1, const float* __restrict__ w2,
                                               const float* __restrict__ wv, unsigned short* __restrict__ w1t,
                                               unsigned short* __restrict__ w2t, unsigned short* __restrict__ wvt) {
  int id = blockIdx.x;
  const float* inp;
  unsigned short* outp;
  int R, C, bx, by;
  size_t zo = 0;
  if (id < 192) {
    inp = w1; outp = w1t; R = 512; C = 1536; bx = id % 24; by = id / 24;
  } else if (id < 384) {
    int i = id - 192;
    inp = w2; outp = w2t; R = 1536; C = 512; bx = i & 7; by = i >> 3;
  } else {
    int i = id - 384;
    inp = wv; outp = wvt; R = 512; C = 64; bx = 0; by = i & 7; zo = (size_t)(i >> 3) * (512 * 64);
  }
  int c0 = bx * 64, r0 = by * 64;
  __shared__ float tile[64][65];
  int t = threadIdx.x;
#pragma unroll
  for (int j = 0; j < 4; ++j) {
    int i = t + j * 256;
    int rr = i >> 4, c4 = i & 15;
    float4 v = *(const float4*)(inp + zo + (size_t)(r0 + rr) * C + c0 + c4 * 4);
    tile[rr][c4 * 4 + 0] = v.x;
    tile[rr][c4 * 4 + 1] = v.y;
    tile[rr][c4 * 4 + 2] = v.z;
    tile[rr][c4 * 4 + 3] = v.w;
  }
  __syncthreads();
#pragma unroll
  for (int j = 0; j < 4; ++j) {
    int u = t + j * 256;
    int cr = u >> 4, q = u & 15;
    ushort4 o;
    o.x = f2bf(tile[q * 4 + 0][cr]);
    o.y = f2bf(tile[q * 4 + 1][cr]);
    o.z = f2bf(tile[q * 4 + 2][cr]);
    o.w = f2bf(tile[q * 4 + 3][cr]);
    *(ushort4*)(outp + zo + (size_t)(c0 + cr) * R + r0 + q * 4) = o;
  }
}

// ---------------- x -> bf16 convert + per-batch column partial sums ----------------
__global__ __launch_bounds__(256) void k_xcvt(const float* __restrict__ x, unsigned short* __restrict__ xb,
                                              float* __restrict__ xsump) {
  int b = blockIdx.x, ch = blockIdx.y, t = threadIdx.x;
  int c4 = (t & 127) * 4;
  int rh = t >> 7;
  const float* xp = x + ((size_t)b * S + ch * 64 + rh * 32) * E;
  unsigned short* xbp = xb + ((size_t)b * S + ch * 64 + rh * 32) * E;
  float ax = 0.f, ay = 0.f, az = 0.f, aw = 0.f;
  for (int s = 0; s < 32; ++s) {
    float4 v = *(const float4*)(xp + (size_t)s * E + c4);
    ax += v.x; ay += v.y; az += v.z; aw += v.w;
    ushort4 u;
    u.x = f2bf(v.x); u.y = f2bf(v.y); u.z = f2bf(v.z); u.w = f2bf(v.w);
    *(ushort4*)(xbp + (size_t)s * E + c4) = u;
  }
  float* xs = xsump + ((size_t)b * 16 + ch * 2 + rh) * E + c4;
  xs[0] = ax; xs[1] = ay; xs[2] = az; xs[3] = aw;
}

// ksum[p]=sum_e xsum[b,e]*wk[h,e,p]; wqk[b,h,e]=0.125*sum_p wq[h,e,p]*ksum[p]; zero sqnorm
__global__ __launch_bounds__(64) void k_wqk(const float* __restrict__ xsump, const float* __restrict__ wq,
                                            const float* __restrict__ wk, float* __restrict__ wqk,
                                            float* __restrict__ sqnorm) {
  int b = blockIdx.x, h = blockIdx.y;
  int p = threadIdx.x;
  if (b == 0 && h == 0 && p < 8) sqnorm[p] = 0.f;
  __shared__ float xsl[E];
  __shared__ float ks[P];
  for (int k = 0; k < 8; ++k) {
    int e = p + k * 64;
    float s = 0.f;
#pragma unroll
    for (int c = 0; c < 16; ++c) s += xsump[((size_t)b * 16 + c) * E + e];
    xsl[e] = s;
  }
  __syncthreads();
  const float* wkh = wk + (size_t)h * E * P;
  float acc = 0.f;
  for (int e = 0; e < E; ++e) acc += xsl[e] * wkh[e * P + p];
  ks[p] = acc;
  __syncthreads();
  const float* wqh = wq + (size_t)h * E * P;
  for (int k = 0; k < E / 64; ++k) {
    int e = threadIdx.x + k * 64;
    float a = 0.f;
#pragma unroll 8
    for (int pp = 0; pp < P; ++pp) a += wqh[e * P + pp] * ks[pp];
    wqk[((size_t)b * H + h) * E + e] = a * 0.125f;
  }
}

__global__ __launch_bounds__(256) void k_scores(const float* __restrict__ x, const float* __restrict__ wqk,
                                                float* __restrict__ scores) {
  int b = blockIdx.x, s0 = blockIdx.y * 64, t = threadIdx.x;
  __shared__ float xs[64][68];
  __shared__ float wt[8][68];
  float acc[2] = {0.f, 0.f};
  for (int ec = 0; ec < E; ec += 64) {
#pragma unroll
    for (int j = 0; j < 4; ++j) {
      int i = t + j * 256;
      int row = i >> 4, c4 = i & 15;
      float4 v = *(const float4*)(x + ((size_t)b * S + s0 + row) * E + ec + c4 * 4);
      *(float4*)&xs[row][c4 * 4] = v;
    }
    if (t < 128) {
      int hr = t >> 4, c4 = t & 15;
      float4 v = *(const float4*)(wqk + ((size_t)b * H + hr) * E + ec + c4 * 4);
      *(float4*)&wt[hr][c4 * 4] = v;
    }
    __syncthreads();
#pragma unroll
    for (int j = 0; j < 2; ++j) {
      int o = t + j * 256;
      int sl = o >> 3, hh = o & 7;
      float a = 0.f;
#pragma unroll
      for (int c4 = 0; c4 < 16; ++c4) {
        float4 xa = *(const float4*)&xs[sl][c4 * 4];
        float4 wa = *(const float4*)&wt[hh][c4 * 4];
        a += xa.x * wa.x + xa.y * wa.y + xa.z * wa.z + xa.w * wa.w;
      }
      acc[j] += a;
    }
    __syncthreads();
  }
#pragma unroll
  for (int j = 0; j < 2; ++j) {
    int o = t + j * 256;
    int sl = o >> 3, hh = o & 7;
    scores[((size_t)b * H + hh) * S + s0 + sl] = acc[j];
  }
}

__global__ __launch_bounds__(256) void k_softmax(const float* __restrict__ scores, float* __restrict__ attw,
                                                 float* __restrict__ att_out) {
  int bh = blockIdx.x, t = threadIdx.x;
  int b = bh >> 3, h = bh & 7;
  float v0 = scores[(size_t)bh * S + t];
  float v1 = scores[(size_t)bh * S + t + 256];
  float m = fmaxf(v0, v1);
#pragma unroll
  for (int off = 32; off; off >>= 1) m = fmaxf(m, __shfl_xor(m, off));
  __shared__ float rm[4], rs[4];
  if ((t & 63) == 0) rm[t >> 6] = m;
  __syncthreads();
  m = fmaxf(fmaxf(rm[0], rm[1]), fmaxf(rm[2], rm[3]));
  float e0 = __expf(v0 - m), e1 = __expf(v1 - m);
  float sm = e0 + e1;
#pragma unroll
  for (int off = 32; off; off >>= 1) sm += __shfl_xor(sm, off);
  if ((t & 63) == 0) rs[t >> 6] = sm;
  __syncthreads();
  float inv = 1.f / (rs[0] + rs[1] + rs[2] + rs[3]);
  float a0 = e0 * inv, a1 = e1 * inv;
  attw[(size_t)bh * S + t] = a0;
  attw[(size_t)bh * S + t + 256] = a1;
  att_out[((size_t)b * S + t) * H + h] = a0;
  att_out[((size_t)b * S + t + 256) * H + h] = a1;
}

// ---------------- MFMA GEMM core: T3 minimum-2-phase, dbuf LDS, BK=64, 1 barrier/K-step.
// LDS layout swizzled: lds[row][g] = G[row][g ^ (row&7)] (8 x 16B granules per row).
template <int KD>
__device__ __forceinline__ void gemm_tile_db(const unsigned short* __restrict__ A,
                                             const unsigned short* __restrict__ Bt,
                                             int lda, int ldb, int m0, int n0,
                                             unsigned short* As, unsigned short* Bs, v4f acc[4][4]) {
  const int t = threadIdx.x;
  const int l = t & 63, w = t >> 6;
  const int wr = w >> 1, wc = w & 1;
  const int ch = l >> 4, r15 = l & 15;
  const int srow = l >> 3;                  // row within 8-row chunk (linear LDS dest)
  const int sg = (l & 7) ^ (srow & 7);      // inverse-swizzled source granule
  constexpr int NT = KD / 64;
  auto stage = [&](int buf, int tt) {
    int kc = tt * 64;
#pragma unroll
    for (int cc = 0; cc < 4; ++cc) {
      int c = w * 4 + cc;                   // 1KB chunk = 8 rows
      int row = c * 8 + srow;
      gl_lds16(A + (size_t)(m0 + row) * lda + kc + sg * 8, As + buf * 8192 + c * 512);
      gl_lds16(Bt + (size_t)(n0 + row) * ldb + kc + sg * 8, Bs + buf * 8192 + c * 512);
    }
  };
  stage(0, 0);
#pragma unroll 2
  for (int tt = 0; tt < NT; ++tt) {
    __syncthreads();                        // drains prefetch (vmcnt) + guards LDS reuse
    if (tt + 1 < NT) stage((tt + 1) & 1, tt + 1);  // issue next tile; flies during MFMA
    const unsigned short* Ab = As + (tt & 1) * 8192;
    const unsigned short* Bb = Bs + (tt & 1) * 8192;
    __builtin_amdgcn_s_setprio(1);
#pragma unroll
    for (int kk = 0; kk < 2; ++kk) {
      v8s af[4], bfr[4];
#pragma unroll
      for (int i = 0; i < 4; ++i) {
        int ra = wr * 64 + i * 16 + r15;
        af[i] = *(const v8s*)(Ab + ra * 64 + ((kk * 4 + ch) ^ (ra & 7)) * 8);
        int rb = wc * 64 + i * 16 + r15;
        bfr[i] = *(const v8s*)(Bb + rb * 64 + ((kk * 4 + ch) ^ (rb & 7)) * 8);
      }
#pragma unroll
      for (int i = 0; i < 4; ++i)
#pragma unroll
        for (int j = 0; j < 4; ++j)
          acc[i][j] = __builtin_amdgcn_mfma_f32_16x16x32_bf16(af[i], bfr[j], acc[i][j], 0, 0, 0);
    }
    __builtin_amdgcn_s_setprio(0);
  }
}

// V-projection GEMM: vb[(b,s)][h*64+p] = bf16((xb @ wv)*attw); sqnorm[h] += sum o^2
__global__ __launch_bounds__(256) void k_gemm_v(const unsigned short* __restrict__ xb,
                                                const unsigned short* __restrict__ wvt,
                                                const float* __restrict__ attw, unsigned short* __restrict__ vb,
                                                float* __restrict__ sqnorm) {
  __shared__ alignas(16) unsigned short As[16384], Bs[16384];
  int m0 = blockIdx.x * 128, n0 = blockIdx.y * 128;
  v4f acc[4][4] = {};
  gemm_tile_db<512>(xb, wvt, 512, 512, m0, n0, As, Bs, acc);
  int t = threadIdx.x, l = t & 63, w = t >> 6, wr = w >> 1, wc = w & 1;
  int h = blockIdx.y * 2 + wc;
  float ssq = 0.f;
#pragma unroll
  for (int i = 0; i < 4; ++i) {
#pragma unroll
    for (int q = 0; q < 4; ++q) {
      int row = m0 + wr * 64 + i * 16 + (l >> 4) * 4 + q;
      int b = row >> 9, s = row & 511;
      float aw = attw[(size_t)(b * 8 + h) * 512 + s];
#pragma unroll
      for (int j = 0; j < 4; ++j) {
        int gc = n0 + wc * 64 + j * 16 + (l & 15);
        float o = acc[i][j][q] * aw;
        ssq += o * o;
        vb[(size_t)row * 512 + gc] = f2bf(o);
      }
    }
  }
#pragma unroll
  for (int off = 32; off; off >>= 1) ssq += __shfl_xor(ssq, off);
  if (l == 0) atomicAdd(&sqnorm[h], ssq);
}

// LN0 (wave per row, IN-PLACE over xb): xh := bf16(LN(perm(vb)*hs + xh))
__global__ __launch_bounds__(256) void k_ln0(const unsigned short* __restrict__ vb,
                                             unsigned short* xh,
                                             const float* __restrict__ sqnorm, const float* __restrict__ g,
                                             const float* __restrict__ bb) {
  __shared__ unsigned short perm[4][512];
  int t = threadIdx.x, w = t >> 6, l = t & 63;
  int r = blockIdx.x * 4 + w;
  *(v8s*)&perm[w][l * 8] = *(const v8s*)(vb + (size_t)r * 512 + l * 8);
  __syncthreads();
  v8s xv = *(const v8s*)(xh + (size_t)r * 512 + l * 8);
  float v[8];
#pragma unroll
  for (int j = 0; j < 8; ++j) {
    float hs = rsqrtf(fmaxf(sqnorm[j], 1e-12f));
    v[j] = bf2f(perm[w][j * 64 + l]) * hs + bf2f((unsigned short)xv[j]);
  }
  float sum = 0.f, sq = 0.f;
#pragma unroll
  for (int j = 0; j < 8; ++j) { sum += v[j]; sq += v[j] * v[j]; }
#pragma unroll
  for (int off = 32; off; off >>= 1) {
    sum += __shfl_xor(sum, off);
    sq += __shfl_xor(sq, off);
  }
  float mean = sum * (1.f / E);
  float var = fmaxf(sq * (1.f / E) - mean * mean, 0.f);
  float rstd = rsqrtf(var + 1e-3f);
  float4 g0 = *(const float4*)(g + l * 8), g1 = *(const float4*)(g + l * 8 + 4);
  float4 b0 = *(const float4*)(bb + l * 8), b1 = *(const float4*)(bb + l * 8 + 4);
  float gg[8] = {g0.x, g0.y, g0.z, g0.w, g1.x, g1.y, g1.z, g1.w};
  float bbv[8] = {b0.x, b0.y, b0.z, b0.w, b1.x, b1.y, b1.z, b1.w};
  v8s hv;
#pragma unroll
  for (int j = 0; j < 8; ++j) hv[j] = (short)f2bf((v[j] - mean) * rstd * gg[j] + bbv[j]);
  *(v8s*)(xh + (size_t)r * 512 + l * 8) = hv;
}

// FFN1: p1 = bf16(leaky_relu(hb @ w1 + b1)); rsump[row][nb*2+wc] = partial sumsq
__global__ __launch_bounds__(256) void k_ffn1(const unsigned short* __restrict__ hb,
                                              const unsigned short* __restrict__ w1t,
                                              const float* __restrict__ b1, unsigned short* __restrict__ p1,
                                              float* __restrict__ rsump) {
  __shared__ alignas(16) unsigned short As[16384], Bs[16384];
  int m0 = blockIdx.x * 128, n0 = blockIdx.y * 128;
  v4f acc[4][4] = {};
  gemm_tile_db<512>(hb, w1t, 512, 512, m0, n0, As, Bs, acc);
  int t = threadIdx.x, l = t & 63, w = t >> 6, wr = w >> 1, wc = w & 1;
  int colb = n0 + wc * 64 + (l & 15);
  float bias[4];
#pragma unroll
  for (int j = 0; j < 4; ++j) bias[j] = b1[colb + j * 16];
#pragma unroll
  for (int i = 0; i < 4; ++i) {
#pragma unroll
    for (int q = 0; q < 4; ++q) {
      int row = m0 + wr * 64 + i * 16 + (l >> 4) * 4 + q;
      float ps = 0.f;
#pragma unroll
      for (int j = 0; j < 4; ++j) {
        float v = acc[i][j][q] + bias[j];
        v = v > 0.f ? v : 0.2f * v;
        ps += v * v;
        p1[(size_t)row * FF + colb + j * 16] = f2bf(v);
      }
#pragma unroll
      for (int m = 1; m < 16; m <<= 1) ps += __shfl_xor(ps, m);
      if ((l & 15) == 0) rsump[(size_t)row * 24 + blockIdx.y * 2 + wc] = ps;
    }
  }
}

__global__ __launch_bounds__(256) void k_rinv(const float* __restrict__ rsump, float* __restrict__ rinv) {
  int r = blockIdx.x * 256 + threadIdx.x;
  float s = 0.f;
#pragma unroll
  for (int k = 0; k < 24; ++k) s += rsump[(size_t)r * 24 + k];
  rinv[r] = rsqrtf(fmaxf(s, 1e-12f));
}

// FFN2: p2b = bf16((p1 @ w2)*rinv + b2 + hb)
__global__ __launch_bounds__(256) void k_ffn2(const unsigned short* __restrict__ p1,
                                              const unsigned short* __restrict__ w2t,
                                              const float* __restrict__ rinv, const float* __restrict__ b2,
                                              const unsigned short* __restrict__ hb,
                                              unsigned short* __restrict__ p2b) {
  __shared__ alignas(16) unsigned short As[16384], Bs[16384];
  int m0 = blockIdx.x * 128, n0 = blockIdx.y * 128;
  v4f acc[4][4] = {};
  gemm_tile_db<1536>(p1, w2t, 1536, 1536, m0, n0, As, Bs, acc);
  int t = threadIdx.x, l = t & 63, w = t >> 6, wr = w >> 1, wc = w & 1;
  int colb = n0 + wc * 64 + (l & 15);
  float bias[4];
#pragma unroll
  for (int j = 0; j < 4; ++j) bias[j] = b2[colb + j * 16];
#pragma unroll
  for (int i = 0; i < 4; ++i) {
#pragma unroll
    for (int q = 0; q < 4; ++q) {
      int row = m0 + wr * 64 + i * 16 + (l >> 4) * 4 + q;
      float rv = rinv[row];
#pragma unroll
      for (int j = 0; j < 4; ++j) {
        size_t idx = (size_t)row * 512 + colb + j * 16;
        float o = acc[i][j][q] * rv + bias[j] + bf2f(hb[idx]);
        p2b[idx] = f2bf(o);
      }
    }
  }
}

// LN1 (wave per row): out = LN(p2b)
__global__ __launch_bounds__(256) void k_ln1(const unsigned short* __restrict__ p2b, const float* __restrict__ g,
                                             const float* __restrict__ bb, float* __restrict__ outp) {
  int t = threadIdx.x, w = t >> 6, l = t & 63;
  int r = blockIdx.x * 4 + w;
  v8s pv = *(const v8s*)(p2b + (size_t)r * 512 + l * 8);
  float v[8];
#pragma unroll
  for (int j = 0; j < 8; ++j) v[j] = bf2f((unsigned short)pv[j]);
  float sum = 0.f, sq = 0.f;
#pragma unroll
  for (int j = 0; j < 8; ++j) { sum += v[j]; sq += v[j] * v[j]; }
#pragma unroll
  for (int off = 32; off; off >>= 1) {
    sum += __shfl_xor(sum, off);
    sq += __shfl_xor(sq, off);
  }
  float mean = sum * (1.f / E);
  float var = fmaxf(sq * (1.f / E) - mean * mean, 0.f);
  float rstd = rsqrtf(var + 1e-3f);
  float4 g0 = *(const float4*)(g + l * 8), g1 = *(const float4*)(g + l * 8 + 4);
  float4 b0 = *(const float4*)(bb + l * 8), b1 = *(const float4*)(bb + l * 8 + 4);
  float gg[8] = {g0.x, g0.y, g0.z, g0.w, g1.x, g1.y, g1.z, g1.w};
  float bbv[8] = {b0.x, b0.y, b0.z, b0.w, b1.x, b1.y, b1.z, b1.w};
  float4 o0, o1;
  o0.x = (v[0] - mean) * rstd * gg[0] + bbv[0];
  o0.y = (v[1] - mean) * rstd * gg[1] + bbv[1];
  o0.z = (v[2] - mean) * rstd * gg[2] + bbv[2];
  o0.w = (v[3] - mean) * rstd * gg[3] + bbv[3];
  o1.x = (v[4] - mean) * rstd * gg[4] + bbv[4];
  o1.y = (v[5] - mean) * rstd * gg[5] + bbv[5];
  o1.z = (v[6] - mean) * rstd * gg[6] + bbv[6];
  o1.w = (v[7] - mean) * rstd * gg[7] + bbv[7];
  *(float4*)(outp + (size_t)r * 512 + l * 8) = o0;
  *(float4*)(outp + (size_t)r * 512 + l * 8 + 4) = o1;
}

}  // namespace

extern "C" void kernel_launch(void* const* d_in, const int* in_sizes, int n_in,
                              void* d_out, int out_size, void* d_ws, size_t ws_size,
                              hipStream_t stream) {
  const float* x = (const float*)d_in[0];
  const float* wq = (const float*)d_in[1];
  const float* wk = (const float*)d_in[2];
  const float* wv = (const float*)d_in[3];
  const float* ln0_g = (const float*)d_in[4];
  const float* ln0_b = (const float*)d_in[5];
  const float* w1 = (const float*)d_in[6];
  const float* b1 = (const float*)d_in[7];
  const float* w2 = (const float*)d_in[8];
  const float* b2 = (const float*)d_in[9];
  const float* ln1_g = (const float*)d_in[10];
  const float* ln1_b = (const float*)d_in[11];

  float* att_out = (float*)d_out;                  // [B,S,H]
  float* outp = (float*)d_out + (size_t)B * S * H; // [B,S,E]

  char* ws = (char*)d_ws;
  float* xsump = (float*)(ws + 0);                        // 1 MB  [B][16][E]
  float* wqkb = (float*)(ws + 1048576);                   // 512 KB
  float* scores = (float*)(ws + 1572864);                 // 512 KB
  float* attw = (float*)(ws + 2097152);                   // 512 KB
  float* sqnorm = (float*)(ws + 2621440);                 // 4 KB (pad)
  float* rsump = (float*)(ws + 2625536);                  // 1.5 MB [BS][24]
  float* rinv = (float*)(ws + 4198400);                   // 64 KB
  unsigned short* w1t = (unsigned short*)(ws + 4263936);  // 1.5 MB [FF][E]
  unsigned short* w2t = (unsigned short*)(ws + 5836800);  // 1.5 MB [E][FF]
  unsigned short* wvt = (unsigned short*)(ws + 7409664);  // 512 KB [H*P][E]
  unsigned short* xb = (unsigned short*)(ws + 7933952);   // 16 MB [BS][E] bf16 (hb aliases after ln0)
  unsigned short* vb = (unsigned short*)(ws + 24711168);  // 16 MB [BS][512] bf16 (p2b aliases)
  unsigned short* p1 = (unsigned short*)(ws + 41488384);  // 48 MB [BS][FF] bf16
  unsigned short* hb = xb;                                // ln0 writes in place
  unsigned short* p2b = vb;                               // vb dead after ln0

  k_wprep<<<448, 256, 0, stream>>>(w1, w2, wv, w1t, w2t, wvt);
  k_xcvt<<<dim3(B, 8), 256, 0, stream>>>(x, xb, xsump);
  k_wqk<<<dim3(B, H), 64, 0, stream>>>(xsump, wq, wk, wqkb, sqnorm);
  k_scores<<<dim3(B, S / 64), 256, 0, stream>>>(x, wqkb, scores);
  k_softmax<<<B * H, 256, 0, stream>>>(scores, attw, att_out);
  k_gemm_v<<<dim3(BS / 128, 4), 256, 0, stream>>>(xb, wvt, attw, vb, sqnorm);
  k_ln0<<<BS / 4, 256, 0, stream>>>(vb, xb, sqnorm, ln0_g, ln0_b);
  k_ffn1<<<dim3(BS / 128, FF / 128), 256, 0, stream>>>(hb, w1t, b1, p1, rsump);
  k_rinv<<<BS / 256, 256, 0, stream>>>(rsump, rinv);
  k_ffn2<<<dim3(BS / 128, E / 128), 256, 0, stream>>>(p1, w2t, rinv, b2, hb, p2b);
  k_ln1<<<BS / 4, 256, 0, stream>>>(p2b, ln1_g, ln1_b, outp);
}